// Round 2
// baseline (134.020 us; speedup 1.0000x reference)
//
#include <hip/hip_runtime.h>
#include <hip/hip_bf16.h>

typedef _Float16 f16x8 __attribute__((ext_vector_type(8)));
typedef float    f32x4 __attribute__((ext_vector_type(4)));

#define IMG_H 400
#define IMG_W 400
#define NPIX  160000
#define K1    363      // 3 * 11 * 11
#define NKT1  12       // ceil(363/32) -> K padded to 384
#define C1    128
#define C2    64

#define W1P_ELEMS (NKT1*8*64*8)  // 49152
#define W2P_ELEMS (4*4*64*8)     // 8192
#define W3P_ELEMS (2*64*8)       // 1024

#define H1_STRIDE 136   // 128 + 8 pad: breaks 16-way LDS bank conflict on a-frag reads
#define H2_STRIDE 72    // 64 + 8

// ---------------------------------------------------------------------------
// Pack fp32 W1/W2/W3 (row-major [K][N]) into fp16 MFMA B-fragment order:
//   frag element (ktile, ntile, lane, j) = W[k = ktile*32 + (lane>>4)*8 + j]
//                                           [n = ntile*16 + (lane&15)]
// so the main kernel loads one contiguous 16B chunk per lane per frag.
// Zero-pads W1 K: 363 -> 384, and W3 N: 8 -> 16.
// ---------------------------------------------------------------------------
__global__ void pack_weights(const float* __restrict__ W1,
                             const float* __restrict__ W2,
                             const float* __restrict__ W3,
                             _Float16* __restrict__ ws)
{
    const int total = W1P_ELEMS + W2P_ELEMS + W3P_ELEMS;
    for (int i = blockIdx.x * blockDim.x + threadIdx.x; i < total;
         i += gridDim.x * blockDim.x) {
        if (i < W1P_ELEMS) {
            int e = i;
            int j = e & 7, lane = (e >> 3) & 63, nt = (e >> 9) & 7, kt = e >> 12;
            int q = lane >> 4, n15 = lane & 15;
            int k = kt * 32 + q * 8 + j;
            int n = nt * 16 + n15;
            ws[i] = (k < K1) ? (_Float16)W1[k * C1 + n] : (_Float16)0.0f;
        } else if (i < W1P_ELEMS + W2P_ELEMS) {
            int e = i - W1P_ELEMS;
            int j = e & 7, lane = (e >> 3) & 63, nt = (e >> 9) & 3, kt = e >> 11;
            int q = lane >> 4, n15 = lane & 15;
            ws[i] = (_Float16)W2[(kt * 32 + q * 8 + j) * C2 + nt * 16 + n15];
        } else {
            int e = i - W1P_ELEMS - W2P_ELEMS;
            int j = e & 7, lane = (e >> 3) & 63, kt = e >> 9;
            int q = lane >> 4, n15 = lane & 15;
            ws[i] = (n15 < 8) ? (_Float16)W3[(kt * 32 + q * 8 + j) * 8 + n15]
                              : (_Float16)0.0f;
        }
    }
}

// ---------------------------------------------------------------------------
// Fused: im2col -> 363x128 -> leaky -> 128x64 -> leaky -> 64x8 -> L2-normalize
// Block = 256 threads (4 waves), 128 pixels/block, 32 pixels/wave
// (2 m-tiles of 16). All MFMA 16x16x32 f16, fp32 accum.
// Layouts (HW-verified per guide): A[m=lane&15][k=q*8+j],
// B[k=q*8+j][n=lane&15], D[m=q*4+r][n=lane&15], q = lane>>4.
// ---------------------------------------------------------------------------
__global__ __launch_bounds__(256) void fused_unfold_mlp(
    const float* __restrict__ xp,
    const float* __restrict__ b1,
    const float* __restrict__ b2,
    const float* __restrict__ b3,
    const _Float16* __restrict__ wpack,
    float* __restrict__ out)
{
    __shared__ _Float16 hbuf[4 * 32 * H1_STRIDE];   // 34816 B

    const int tid  = threadIdx.x;
    const int wave = tid >> 6;
    const int lane = tid & 63;
    const int q    = lane >> 4;
    const int n15  = lane & 15;

    const int pbase = blockIdx.x * 128 + wave * 32;

    // pixel coordinates of the two A-frag rows this lane feeds
    int py[2], px[2];
#pragma unroll
    for (int t = 0; t < 2; ++t) {
        int p = pbase + t * 16 + n15;
        py[t] = p / IMG_W;
        px[t] = p - py[t] * IMG_W;
    }

    const _Float16* w1p = wpack;
    const _Float16* w2p = wpack + W1P_ELEMS;
    const _Float16* w3p = wpack + W1P_ELEMS + W2P_ELEMS;

    _Float16* hw = &hbuf[wave * 32 * H1_STRIDE];   // wave-private staging

    // ---------------- layer 1: [32 x 384] @ [384 x 128] ----------------
    f32x4 acc[2][8];
#pragma unroll
    for (int t = 0; t < 2; ++t)
#pragma unroll
        for (int nt = 0; nt < 8; ++nt)
            acc[t][nt] = (f32x4){0.f, 0.f, 0.f, 0.f};

    for (int kt = 0; kt < NKT1; ++kt) {
        f16x8 afrag[2];
#pragma unroll
        for (int j = 0; j < 8; ++j) {
            int k  = kt * 32 + q * 8 + j;
            int c  = k / 121;          // channel  (magic-mul)
            int r  = k - c * 121;
            int ki = r / 11;           // kernel row
            int kj = r - ki * 11;      // kernel col
            bool kv = (k < K1);
#pragma unroll
            for (int t = 0; t < 2; ++t) {
                int iy = py[t] + ki - 5;
                int ix = px[t] + kj - 5;
                bool valid = kv && ((unsigned)iy < (unsigned)IMG_H)
                                && ((unsigned)ix < (unsigned)IMG_W);
                int idx = valid ? (c * NPIX + iy * IMG_W + ix) : 0;
                float vv = xp[idx];
                afrag[t][j] = valid ? (_Float16)vv : (_Float16)0.0f;
            }
        }
#pragma unroll
        for (int nt = 0; nt < 8; ++nt) {
            f16x8 bfrag = *(const f16x8*)(w1p + ((kt * 8 + nt) * 64 + lane) * 8);
            acc[0][nt] = __builtin_amdgcn_mfma_f32_16x16x32_f16(afrag[0], bfrag, acc[0][nt], 0, 0, 0);
            acc[1][nt] = __builtin_amdgcn_mfma_f32_16x16x32_f16(afrag[1], bfrag, acc[1][nt], 0, 0, 0);
        }
    }

    // epilogue 1: + b1, leaky(0.01), h1 -> LDS as fp16
#pragma unroll
    for (int nt = 0; nt < 8; ++nt) {
        float bb = b1[nt * 16 + n15];
#pragma unroll
        for (int t = 0; t < 2; ++t)
#pragma unroll
            for (int r = 0; r < 4; ++r) {
                float v = acc[t][nt][r] + bb;
                v = v > 0.f ? v : 0.01f * v;
                int pl = t * 16 + q * 4 + r;
                hw[pl * H1_STRIDE + nt * 16 + n15] = (_Float16)v;
            }
    }
    __syncthreads();

    // ---------------- layer 2: [32 x 128] @ [128 x 64] ----------------
    f32x4 acc2[2][4];
#pragma unroll
    for (int t = 0; t < 2; ++t)
#pragma unroll
        for (int nt = 0; nt < 4; ++nt)
            acc2[t][nt] = (f32x4){0.f, 0.f, 0.f, 0.f};

#pragma unroll
    for (int kt = 0; kt < 4; ++kt) {
        f16x8 afrag[2];
#pragma unroll
        for (int t = 0; t < 2; ++t)
            afrag[t] = *(const f16x8*)&hw[(t * 16 + n15) * H1_STRIDE + kt * 32 + q * 8];
#pragma unroll
        for (int nt = 0; nt < 4; ++nt) {
            f16x8 bfrag = *(const f16x8*)(w2p + ((kt * 4 + nt) * 64 + lane) * 8);
            acc2[0][nt] = __builtin_amdgcn_mfma_f32_16x16x32_f16(afrag[0], bfrag, acc2[0][nt], 0, 0, 0);
            acc2[1][nt] = __builtin_amdgcn_mfma_f32_16x16x32_f16(afrag[1], bfrag, acc2[1][nt], 0, 0, 0);
        }
    }
    __syncthreads();   // all h1 reads done before overwriting with h2

    // epilogue 2: + b2, leaky, h2 -> LDS as fp16
#pragma unroll
    for (int nt = 0; nt < 4; ++nt) {
        float bb = b2[nt * 16 + n15];
#pragma unroll
        for (int t = 0; t < 2; ++t)
#pragma unroll
            for (int r = 0; r < 4; ++r) {
                float v = acc2[t][nt][r] + bb;
                v = v > 0.f ? v : 0.01f * v;
                int pl = t * 16 + q * 4 + r;
                hw[pl * H2_STRIDE + nt * 16 + n15] = (_Float16)v;
            }
    }
    __syncthreads();

    // ---------------- layer 3: [32 x 64] @ [64 x 16(pad)] ----------------
    f32x4 acc3[2];
    acc3[0] = (f32x4){0.f, 0.f, 0.f, 0.f};
    acc3[1] = (f32x4){0.f, 0.f, 0.f, 0.f};
#pragma unroll
    for (int kt = 0; kt < 2; ++kt) {
        f16x8 afrag[2];
#pragma unroll
        for (int t = 0; t < 2; ++t)
            afrag[t] = *(const f16x8*)&hw[(t * 16 + n15) * H2_STRIDE + kt * 32 + q * 8];
        f16x8 bfrag = *(const f16x8*)(w3p + (kt * 64 + lane) * 8);
        acc3[0] = __builtin_amdgcn_mfma_f32_16x16x32_f16(afrag[0], bfrag, acc3[0], 0, 0, 0);
        acc3[1] = __builtin_amdgcn_mfma_f32_16x16x32_f16(afrag[1], bfrag, acc3[1], 0, 0, 0);
    }

    // epilogue 3: + b3, L2-normalize over the 8 channels (lanes n15=0..7 of
    // each quad hold one pixel's channels; lanes 8..15 are zero pads)
    float bb3 = (n15 < 8) ? b3[n15] : 0.0f;
#pragma unroll
    for (int t = 0; t < 2; ++t) {
#pragma unroll
        for (int r = 0; r < 4; ++r) {
            float v = acc3[t][r] + bb3;
            float s = v * v;
            s += __shfl_xor(s, 1);
            s += __shfl_xor(s, 2);
            s += __shfl_xor(s, 4);
            float inv = 1.0f / fmaxf(sqrtf(s), 1e-12f);
            if (n15 < 8) {
                int p = pbase + t * 16 + q * 4 + r;
                out[p * 8 + n15] = v * inv;
            }
        }
    }
}

extern "C" void kernel_launch(void* const* d_in, const int* in_sizes, int n_in,
                              void* d_out, int out_size, void* d_ws, size_t ws_size,
                              hipStream_t stream) {
    const float* x  = (const float*)d_in[0];
    const float* W1 = (const float*)d_in[1];
    const float* b1 = (const float*)d_in[2];
    const float* W2 = (const float*)d_in[3];
    const float* b2 = (const float*)d_in[4];
    const float* W3 = (const float*)d_in[5];
    const float* b3 = (const float*)d_in[6];
    float* out = (float*)d_out;
    _Float16* ws = (_Float16*)d_ws;   // needs 116736 B

    pack_weights<<<dim3(228), dim3(256), 0, stream>>>(W1, W2, W3, ws);
    fused_unfold_mlp<<<dim3(NPIX / 128), dim3(256), 0, stream>>>(x, b1, b2, b3, ws, out);
}

// Round 3
// 133.748 us; speedup vs baseline: 1.0020x; 1.0020x over previous
//
#include <hip/hip_runtime.h>
#include <hip/hip_bf16.h>
#include <math.h>

typedef _Float16 f16x8 __attribute__((ext_vector_type(8)));
typedef _Float16 f16x4 __attribute__((ext_vector_type(4)));
typedef float    f32x4 __attribute__((ext_vector_type(4)));

#define IMG   400
#define NPIX  160000
#define NKT1  18                  // K1 padded: (c,ki,kj)->(3,12,16) = 576
#define W1P   (NKT1*8*64*8)       // 73728 f16
#define W2P   (4*4*64*8)          // 8192
#define W3P   (2*64*8)            // 1024
#define H1S   136                 // h1 stride (128+8): breaks pow2 bank aliasing
#define H2S   72                  // h2 stride (64+8)
#define XPH   1938                // x-tile elems per phase: 3c * 19rows * 34slots

// ---------------------------------------------------------------------------
// Pack fp32 weights into fp16 MFMA A-fragment order (A[m=lane&15][k=q*8+j]).
// W1 uses permuted K: k' = (c*12 + ki)*16 + kj  (ki 11->12 pad, kj 11->16 pad,
// pads are zero). Reads coalesced (n fastest); writes scattered (fire&forget).
// ---------------------------------------------------------------------------
__global__ void pack_weights(const float* __restrict__ W1,
                             const float* __restrict__ W2,
                             const float* __restrict__ W3,
                             _Float16* __restrict__ ws)
{
    int i = blockIdx.x * blockDim.x + threadIdx.x;
    if (i < 576 * 128) {                      // W1 region
        int kp = i >> 7, n = i & 127;
        int kt = kp >> 5, kl = kp & 31, q = kl >> 3, j = kl & 7;
        int pair = kp >> 4, kj = kp & 15;
        int c = pair / 12, ki = pair % 12;
        int mt = n >> 4, n15 = n & 15;
        int lane = q * 16 + n15;
        float v = (ki < 11 && kj < 11) ? W1[(c * 121 + ki * 11 + kj) * 128 + n] : 0.0f;
        ws[((kt * 8 + mt) * 64 + lane) * 8 + j] = (_Float16)v;
    } else if (i < 576 * 128 + 128 * 64) {    // W2 region
        int e = i - 576 * 128;
        int kp = e >> 6, n = e & 63;
        int kt = kp >> 5, kl = kp & 31, q = kl >> 3, j = kl & 7;
        int mt = n >> 4, n15 = n & 15;
        int lane = q * 16 + n15;
        ws[W1P + ((kt * 4 + mt) * 64 + lane) * 8 + j] = (_Float16)W2[kp * 64 + n];
    } else if (i < 576 * 128 + 128 * 64 + 64 * 16) {  // W3 region (N pad 8->16)
        int e = i - 576 * 128 - 128 * 64;
        int kp = e >> 4, n = e & 15;
        int kt = kp >> 5, kl = kp & 31, q = kl >> 3, j = kl & 7;
        int lane = q * 16 + n;
        float v = (n < 8) ? W3[kp * 8 + n] : 0.0f;
        ws[W1P + W2P + (kt * 64 + lane) * 8 + j] = (_Float16)v;
    }
}

// ---------------------------------------------------------------------------
// Fused conv-MLP. Block = 256 thr (4 waves) = 16x8 pixel tile; wave = 2 rows
// of 16 pixels (2 n-tiles). MFMA roles: A = weights (m = out-ch),
// B = pixels (n = pixel). Verified layouts: A[m=lane&15][k=q*8+j],
// B[k=q*8+j][n=lane&15], D[row m=q*4+r][col n=lane&15].
// x halo staged in LDS fp16, dual-phase (even/odd alignment) so every
// B-fragment = 4 ds_read_b32 at compile-time immediates.
// ---------------------------------------------------------------------------
__global__ __launch_bounds__(256, 3) void fused_unfold_mlp(
    const float* __restrict__ x,
    const float* __restrict__ b1,
    const float* __restrict__ b2,
    const float* __restrict__ b3,
    const _Float16* __restrict__ wpack,
    float* __restrict__ out)
{
    __shared__ __align__(16) _Float16 xs[2 * XPH];   // 7752 B
    __shared__ __align__(16) _Float16 hb[4 * 32 * H1S]; // 34816 B

    const int tid  = threadIdx.x;
    const int wave = tid >> 6;
    const int lane = tid & 63;
    const int q    = lane >> 4;
    const int n15  = lane & 15;
    const int bx   = blockIdx.x;   // 0..24 (col tiles)
    const int by   = blockIdx.y;   // 0..49 (row tiles)

    // ---- stage x halo: rows gy in [by*8-5, by*8+13], cols gx in [bx*16-6, +28]
    // P0 slot s holds col s-5; P1 slot s holds col s-6 (dual phase for dword
    // alignment). All 2*3*19*34 slots written (zero outside image) -> no NaN.
    for (int w = tid; w < 3 * 19 * 35; w += 256) {
        int col = w % 35;              // 0..34 -> gcol offset col-6
        int rc  = w / 35;
        int row = rc % 19, c = rc / 19;
        int gy = by * 8 + row - 5;
        int gx = bx * 16 + col - 6;
        float v = 0.0f;
        if ((unsigned)gy < (unsigned)IMG && (unsigned)gx < (unsigned)IMG)
            v = x[c * NPIX + gy * IMG + gx];
        _Float16 hv = (_Float16)v;
        int base = (c * 19 + row) * 34;
        if (col >= 1)  xs[base + col - 1] = hv;        // P0
        if (col <= 33) xs[XPH + base + col] = hv;      // P1
    }
    __syncthreads();

    const _Float16* w1p = wpack;
    const _Float16* w2p = wpack + W1P;
    const _Float16* w3p = wpack + W1P + W2P;
    _Float16* hw = &hb[wave * 32 * H1S];     // wave-private h staging

    // B-fragment base dword index into xs (per n-tile t)
    const uint32_t* xsd = (const uint32_t*)xs;
    const int h = q >> 1;                       // k-half -> pair select
    const int u = n15 + (n15 & 1) + ((q & 1) << 3);   // aligned slot start
    const int bdw0 = (n15 & 1) * (XPH / 2) + (u >> 1);
    int bdwt[2];
#pragma unroll
    for (int t = 0; t < 2; ++t)
        bdwt[t] = bdw0 + (wave * 2 + t + h) * 17;

    // ---------------- layer 1: 128ch x (576)K x 32pix ----------------
    f32x4 acc1[2][8];
#pragma unroll
    for (int t = 0; t < 2; ++t)
#pragma unroll
        for (int mt = 0; mt < 8; ++mt)
            acc1[t][mt] = (f32x4){0.f, 0.f, 0.f, 0.f};

#pragma unroll
    for (int kt = 0; kt < NKT1; ++kt) {
        const int rim = ((kt / 6) * 19 + 2 * (kt % 6)) * 17;  // row imm (dwords)
        f16x8 bf[2];
#pragma unroll
        for (int t = 0; t < 2; ++t) {
            union { uint32_t u[4]; f16x8 f; } cv;
#pragma unroll
            for (int m = 0; m < 4; ++m)
                cv.u[m] = xsd[bdwt[t] + rim + m];
            bf[t] = cv.f;
        }
#pragma unroll
        for (int mt = 0; mt < 8; ++mt) {
            f16x8 af = *(const f16x8*)(w1p + ((kt * 8 + mt) * 64 + lane) * 8);
            acc1[0][mt] = __builtin_amdgcn_mfma_f32_16x16x32_f16(af, bf[0], acc1[0][mt], 0, 0, 0);
            acc1[1][mt] = __builtin_amdgcn_mfma_f32_16x16x32_f16(af, bf[1], acc1[1][mt], 0, 0, 0);
        }
    }

    // epilogue 1: +b1, leaky, h1[pix][ch] fp16 via b64 writes (4 ch/lane contig)
#pragma unroll
    for (int mt = 0; mt < 8; ++mt) {
        float4 bb = *(const float4*)(b1 + mt * 16 + q * 4);
#pragma unroll
        for (int t = 0; t < 2; ++t) {
            f16x4 hv;
#pragma unroll
            for (int r = 0; r < 4; ++r) {
                float v = acc1[t][mt][r] + ((const float*)&bb)[r];
                v = fmaxf(v, 0.01f * v);
                hv[r] = (_Float16)v;
            }
            *(f16x4*)(hw + (t * 16 + n15) * H1S + mt * 16 + q * 4) = hv;
        }
    }
    // wave-private LDS: in-order DS per wave, no barrier needed

    // ---------------- layer 2: 64ch x 128K x 32pix ----------------
    f32x4 acc2[2][4];
#pragma unroll
    for (int t = 0; t < 2; ++t)
#pragma unroll
        for (int mt = 0; mt < 4; ++mt)
            acc2[t][mt] = (f32x4){0.f, 0.f, 0.f, 0.f};

#pragma unroll
    for (int kt = 0; kt < 4; ++kt) {
        f16x8 bf[2];
#pragma unroll
        for (int t = 0; t < 2; ++t)
            bf[t] = *(const f16x8*)(hw + (t * 16 + n15) * H1S + kt * 32 + q * 8);
#pragma unroll
        for (int mt = 0; mt < 4; ++mt) {
            f16x8 af = *(const f16x8*)(w2p + ((kt * 4 + mt) * 64 + lane) * 8);
            acc2[0][mt] = __builtin_amdgcn_mfma_f32_16x16x32_f16(af, bf[0], acc2[0][mt], 0, 0, 0);
            acc2[1][mt] = __builtin_amdgcn_mfma_f32_16x16x32_f16(af, bf[1], acc2[1][mt], 0, 0, 0);
        }
    }

    // epilogue 2: +b2, leaky, h2[pix][ch] (reuses hw; reads complete first)
#pragma unroll
    for (int mt = 0; mt < 4; ++mt) {
        float4 bb = *(const float4*)(b2 + mt * 16 + q * 4);
#pragma unroll
        for (int t = 0; t < 2; ++t) {
            f16x4 hv;
#pragma unroll
            for (int r = 0; r < 4; ++r) {
                float v = acc2[t][mt][r] + ((const float*)&bb)[r];
                v = fmaxf(v, 0.01f * v);
                hv[r] = (_Float16)v;
            }
            *(f16x4*)(hw + (t * 16 + n15) * H2S + mt * 16 + q * 4) = hv;
        }
    }

    // ---------------- layer 3: 8ch(pad16) x 64K x 32pix ----------------
    f32x4 acc3[2];
    acc3[0] = (f32x4){0.f, 0.f, 0.f, 0.f};
    acc3[1] = (f32x4){0.f, 0.f, 0.f, 0.f};
#pragma unroll
    for (int kt = 0; kt < 2; ++kt) {
        f16x8 af = *(const f16x8*)(w3p + (kt * 64 + lane) * 8);
#pragma unroll
        for (int t = 0; t < 2; ++t) {
            f16x8 bf = *(const f16x8*)(hw + (t * 16 + n15) * H2S + kt * 32 + q * 8);
            acc3[t] = __builtin_amdgcn_mfma_f32_16x16x32_f16(af, bf, acc3[t], 0, 0, 0);
        }
    }

    // epilogue 3: +b3, L2-normalize over 8 ch (ch = q*4+r; q>=2 are zero pad),
    // store one float4 (4 ch) per active lane.
    float4 bb3 = make_float4(0.f, 0.f, 0.f, 0.f);
    if (q < 2) bb3 = *(const float4*)(b3 + q * 4);
#pragma unroll
    for (int t = 0; t < 2; ++t) {
        float v0 = acc3[t][0] + bb3.x;
        float v1 = acc3[t][1] + bb3.y;
        float v2 = acc3[t][2] + bb3.z;
        float v3 = acc3[t][3] + bb3.w;
        float s = v0 * v0 + v1 * v1 + v2 * v2 + v3 * v3;
        s += __shfl_xor(s, 16);
        s += __shfl_xor(s, 32);
        float inv = 1.0f / fmaxf(sqrtf(s), 1e-12f);
        if (q < 2) {
            int p = (by * 8 + wave * 2 + t) * IMG + bx * 16 + n15;
            float4 o = make_float4(v0 * inv, v1 * inv, v2 * inv, v3 * inv);
            *(float4*)(out + p * 8 + q * 4) = o;
        }
    }
}

extern "C" void kernel_launch(void* const* d_in, const int* in_sizes, int n_in,
                              void* d_out, int out_size, void* d_ws, size_t ws_size,
                              hipStream_t stream) {
    const float* x  = (const float*)d_in[0];
    const float* W1 = (const float*)d_in[1];
    const float* b1 = (const float*)d_in[2];
    const float* W2 = (const float*)d_in[3];
    const float* b2 = (const float*)d_in[4];
    const float* W3 = (const float*)d_in[5];
    const float* b3 = (const float*)d_in[6];
    float* out = (float*)d_out;
    _Float16* ws = (_Float16*)d_ws;   // needs (73728+8192+1024)*2 = 165888 B

    pack_weights<<<dim3(324), dim3(256), 0, stream>>>(W1, W2, W3, ws);
    fused_unfold_mlp<<<dim3(25, 50), dim3(256), 0, stream>>>(x, b1, b2, b3, ws, out);
}